// Round 1
// baseline (303.960 us; speedup 1.0000x reference)
//
#include <hip/hip_runtime.h>
#include <hip/hip_bf16.h>

// Problem constants
#define Bsz 65536
#define Sdim 256
#define Aag 8
#define NAct 16
#define Kk 10
#define Hh 64
#define ADdim 128
#define Ddim 384

// bf16 weight slab layout per k (element offsets)
#define OFF_KW1 0
#define OFF_AW1 16384
#define OFF_CW1 32768
#define OFF_KW2 57344
#define OFF_AW2 61440
#define OFF_CW2 65536
#define OFF_KW3 69632
#define OFF_AW3 70656
#define OFF_CW3 71680
#define SLAB 72704   // elements per k

typedef float f32x4 __attribute__((ext_vector_type(4)));
typedef __bf16 bf16x8 __attribute__((ext_vector_type(8)));

#define MFMA(a, b, cacc) __builtin_amdgcn_mfma_f32_16x16x32_bf16((a), (b), (cacc), 0, 0, 0)

__device__ __forceinline__ __bf16 f2bf(float f) {
    unsigned int u = __float_as_uint(f);
    unsigned int r = (u + 0x7fffu + ((u >> 16) & 1u)) >> 16;
    union { unsigned short s; __bf16 b; } cv;
    cv.s = (unsigned short)r;
    return cv.b;
}

// ---------------- prep: convert all weights fp32 -> bf16 slabs in ws ----------------
__global__ void prep_weights(const float* __restrict__ kW1, const float* __restrict__ aW1,
                             const float* __restrict__ cW1, const float* __restrict__ kW2,
                             const float* __restrict__ aW2, const float* __restrict__ cW2,
                             const float* __restrict__ kW3, const float* __restrict__ aW3,
                             const float* __restrict__ cW3, __bf16* __restrict__ out) {
    int gid = blockIdx.x * 256 + threadIdx.x;
    if (gid >= SLAB * Kk) return;
    int k = gid / SLAB;
    int off = gid - k * SLAB;
    float v;
    if (off < OFF_AW1)        v = kW1[k * 16384 + off];
    else if (off < OFF_CW1)   v = aW1[k * 16384 + off - OFF_AW1];
    else if (off < OFF_KW2)   v = cW1[k * 24576 + off - OFF_CW1];
    else if (off < OFF_AW2)   v = kW2[k * 4096 + off - OFF_KW2];
    else if (off < OFF_CW2)   v = aW2[k * 4096 + off - OFF_AW2];
    else if (off < OFF_KW3)   v = cW2[k * 4096 + off - OFF_CW2];
    else if (off < OFF_AW3) { int r = off - OFF_KW3; v = (r < 64)  ? kW3[k * 64 + r]  : 0.0f; }
    else if (off < OFF_CW3) { int r = off - OFF_AW3; v = (r < 512) ? aW3[k * 512 + r] : 0.0f; }
    else                    { int r = off - OFF_CW3; v = (r < 512) ? cW3[k * 512 + r] : 0.0f; }
    out[gid] = f2bf(v);
}

// ---------------- staging: weights slab -> padded LDS ----------------
template <int KN>
__device__ __forceinline__ void stage_net(const __bf16* __restrict__ w1src,
                                          const __bf16* __restrict__ w2src,
                                          const __bf16* __restrict__ w3src,
                                          __bf16* W1s, __bf16* W2s, __bf16* W3s, int tid) {
    __syncthreads();  // previous compute must be done reading these buffers
    constexpr int STR = KN + 8;      // padded row stride (bf16 elems)
    constexpr int CPR = KN / 8;      // 16B chunks per row
    constexpr int N1 = 64 * CPR;
#pragma unroll 4
    for (int ci = tid; ci < N1; ci += 256) {
        int row = ci / CPR;
        int cc = ci - row * CPR;
        *(float4*)(W1s + row * STR + cc * 8) = *(const float4*)(w1src + row * KN + cc * 8);
    }
    {
        int ci = tid;
#pragma unroll
        for (int it = 0; it < 2; ++it, ci += 256) {  // 64*64/8 = 512 chunks
            int row = ci >> 3, cc = ci & 7;
            *(float4*)(W2s + row * 72 + cc * 8) = *(const float4*)(w2src + row * 64 + cc * 8);
        }
    }
    if (tid < 128) {  // 16*64/8 = 128 chunks
        int row = tid >> 3, cc = tid & 7;
        *(float4*)(W3s + row * 72 + cc * 8) = *(const float4*)(w3src + row * 64 + cc * 8);
    }
    __syncthreads();
}

// ---------------- one net (3-layer MLP) for this wave's 2 M-tiles ----------------
// MODE 0: key (abs + broadcast), MODE 1: agents (sigmoid), MODE 2: action (sigmoid + combine)
template <int KB, int MODE>
__device__ __forceinline__ void run_net(const bf16x8 (&xf)[2][12],
                                        const __bf16* W1s, const __bf16* W2s, const __bf16* W3s,
                                        __bf16* hs, int wave, int q, int c, int k, int lane,
                                        const float* __restrict__ b1p, const float* __restrict__ b2p,
                                        const float* __restrict__ b3p,
                                        float (&keyv)[2][4], float (&ag)[2][4], float (&outacc)[2][4]) {
    constexpr int STR = KB * 32 + 8;
    // ---- layer 1: [16xKdim] x [Kdimx64] per tile, A from regs, B from LDS ----
    f32x4 acc[2][4];
#pragma unroll
    for (int nt = 0; nt < 4; ++nt) {
        float b = b1p[k * 64 + nt * 16 + c];
        f32x4 bv = {b, b, b, b};
        acc[0][nt] = bv;
        acc[1][nt] = bv;
    }
#pragma unroll
    for (int kb = 0; kb < KB; ++kb) {
        bf16x8 a0 = xf[0][kb];
        bf16x8 a1 = xf[1][kb];
#pragma unroll
        for (int nt = 0; nt < 4; ++nt) {
            bf16x8 bfr = *(const bf16x8*)(W1s + (nt * 16 + c) * STR + kb * 32 + q * 8);
            acc[0][nt] = MFMA(a0, bfr, acc[0][nt]);
            acc[1][nt] = MFMA(a1, bfr, acc[1][nt]);
        }
    }
    // relu -> bf16 -> hs (C-layout -> row-major [row][64])
#pragma unroll
    for (int t = 0; t < 2; ++t) {
        int rb = wave * 32 + t * 16 + q * 4;
#pragma unroll
        for (int nt = 0; nt < 4; ++nt)
#pragma unroll
            for (int i = 0; i < 4; ++i)
                hs[(rb + i) * 72 + nt * 16 + c] = f2bf(fmaxf(acc[t][nt][i], 0.0f));
    }
    // ---- layer 2: [16x64] x [64x64] ----
    f32x4 acc2[2][4];
#pragma unroll
    for (int nt = 0; nt < 4; ++nt) {
        float b = b2p[k * 64 + nt * 16 + c];
        f32x4 bv = {b, b, b, b};
        acc2[0][nt] = bv;
        acc2[1][nt] = bv;
    }
#pragma unroll
    for (int kb = 0; kb < 2; ++kb) {
        bf16x8 a0 = *(const bf16x8*)(hs + (wave * 32 + c) * 72 + kb * 32 + q * 8);
        bf16x8 a1 = *(const bf16x8*)(hs + (wave * 32 + 16 + c) * 72 + kb * 32 + q * 8);
#pragma unroll
        for (int nt = 0; nt < 4; ++nt) {
            bf16x8 bfr = *(const bf16x8*)(W2s + (nt * 16 + c) * 72 + kb * 32 + q * 8);
            acc2[0][nt] = MFMA(a0, bfr, acc2[0][nt]);
            acc2[1][nt] = MFMA(a1, bfr, acc2[1][nt]);
        }
    }
    // relu -> bf16 -> hs (in-place reuse; DS ops from one wave are in-order, reads above precede writes)
#pragma unroll
    for (int t = 0; t < 2; ++t) {
        int rb = wave * 32 + t * 16 + q * 4;
#pragma unroll
        for (int nt = 0; nt < 4; ++nt)
#pragma unroll
            for (int i = 0; i < 4; ++i)
                hs[(rb + i) * 72 + nt * 16 + c] = f2bf(fmaxf(acc2[t][nt][i], 0.0f));
    }
    // ---- layer 3: [16x64] x [64x16-padded] ----
    f32x4 acc3[2];
    {
        float b3 = (MODE == 0) ? b3p[k] : ((c < 8) ? b3p[k * 8 + c] : 0.0f);
        f32x4 bv = {b3, b3, b3, b3};
        acc3[0] = bv;
        acc3[1] = bv;
    }
#pragma unroll
    for (int kb = 0; kb < 2; ++kb) {
        bf16x8 bfr = *(const bf16x8*)(W3s + c * 72 + kb * 32 + q * 8);
        bf16x8 a0 = *(const bf16x8*)(hs + (wave * 32 + c) * 72 + kb * 32 + q * 8);
        bf16x8 a1 = *(const bf16x8*)(hs + (wave * 32 + 16 + c) * 72 + kb * 32 + q * 8);
        acc3[0] = MFMA(a0, bfr, acc3[0]);
        acc3[1] = MFMA(a1, bfr, acc3[1]);
    }
#pragma unroll
    for (int t = 0; t < 2; ++t)
#pragma unroll
        for (int i = 0; i < 4; ++i) {
            if (MODE == 0) {
                float v = fabsf(acc3[t][i]) + 1e-10f;
                keyv[t][i] = __shfl(v, lane & 48, 64);  // broadcast col 0 across the quad's 16 lanes
            } else if (MODE == 1) {
                ag[t][i] = 1.0f / (1.0f + __expf(-acc3[t][i]));
            } else {
                float s = 1.0f / (1.0f + __expf(-acc3[t][i]));
                outacc[t][i] += keyv[t][i] * ag[t][i] * s;
            }
        }
}

// ---------------- main fused kernel ----------------
__global__ __launch_bounds__(256, 2) void qplex_main(
    const float* __restrict__ states, const float* __restrict__ actions,
    const __bf16* __restrict__ wbf,
    const float* __restrict__ kb1, const float* __restrict__ kb2, const float* __restrict__ kb3,
    const float* __restrict__ ab1, const float* __restrict__ ab2, const float* __restrict__ ab3,
    const float* __restrict__ cb1, const float* __restrict__ cb2, const float* __restrict__ cb3,
    float* __restrict__ out) {
    __shared__ __bf16 W1s[64 * 392];  // padded stride = KN+8 (264 or 392)
    __shared__ __bf16 W2s[64 * 72];
    __shared__ __bf16 W3s[16 * 72];
    __shared__ __bf16 hs[128 * 72];   // per-wave h scratch, 32 rows each

    const int tid = threadIdx.x;
    const int lane = tid & 63;
    const int wave = tid >> 6;
    const int q = lane >> 4;
    const int c = lane & 15;

    // ---- load this wave's 32 rows of x = [states | actions_flat] into bf16 A-fragments ----
    bf16x8 xf[2][12];
#pragma unroll
    for (int t = 0; t < 2; ++t) {
        int r = blockIdx.x * 128 + wave * 32 + t * 16 + c;
        const float* srow = states + (size_t)r * Sdim;
        const float* arow = actions + (size_t)r * ADdim;
#pragma unroll
        for (int kb = 0; kb < 12; ++kb) {
            const float* p = (kb < 8) ? (srow + kb * 32 + q * 8) : (arow + (kb - 8) * 32 + q * 8);
            float4 lo = *(const float4*)p;
            float4 hi = *(const float4*)(p + 4);
            bf16x8 v;
            v[0] = f2bf(lo.x); v[1] = f2bf(lo.y); v[2] = f2bf(lo.z); v[3] = f2bf(lo.w);
            v[4] = f2bf(hi.x); v[5] = f2bf(hi.y); v[6] = f2bf(hi.z); v[7] = f2bf(hi.w);
            xf[t][kb] = v;
        }
    }

    float keyv[2][4], ag[2][4], outacc[2][4];
#pragma unroll
    for (int t = 0; t < 2; ++t)
#pragma unroll
        for (int i = 0; i < 4; ++i) outacc[t][i] = 0.0f;

    for (int k = 0; k < Kk; ++k) {
        const __bf16* slab = wbf + (size_t)k * SLAB;
        stage_net<256>(slab + OFF_KW1, slab + OFF_KW2, slab + OFF_KW3, W1s, W2s, W3s, tid);
        run_net<8, 0>(xf, W1s, W2s, W3s, hs, wave, q, c, k, lane, kb1, kb2, kb3, keyv, ag, outacc);
        stage_net<256>(slab + OFF_AW1, slab + OFF_AW2, slab + OFF_AW3, W1s, W2s, W3s, tid);
        run_net<8, 1>(xf, W1s, W2s, W3s, hs, wave, q, c, k, lane, ab1, ab2, ab3, keyv, ag, outacc);
        stage_net<384>(slab + OFF_CW1, slab + OFF_CW2, slab + OFF_CW3, W1s, W2s, W3s, tid);
        run_net<12, 2>(xf, W1s, W2s, W3s, hs, wave, q, c, k, lane, cb1, cb2, cb3, keyv, ag, outacc);
    }

    // ---- epilogue: out[b][a], C-layout row = q*4+i, col(a) = c (<8) ----
    if (c < 8) {
#pragma unroll
        for (int t = 0; t < 2; ++t)
#pragma unroll
            for (int i = 0; i < 4; ++i) {
                int r = blockIdx.x * 128 + wave * 32 + t * 16 + q * 4 + i;
                out[(size_t)r * Aag + c] = outacc[t][i];
            }
    }
}

extern "C" void kernel_launch(void* const* d_in, const int* in_sizes, int n_in,
                              void* d_out, int out_size, void* d_ws, size_t ws_size,
                              hipStream_t stream) {
    const float* states = (const float*)d_in[0];
    const float* actions = (const float*)d_in[1];
    const float* kW1 = (const float*)d_in[2];
    const float* kb1 = (const float*)d_in[3];
    const float* kW2 = (const float*)d_in[4];
    const float* kb2 = (const float*)d_in[5];
    const float* kW3 = (const float*)d_in[6];
    const float* kb3 = (const float*)d_in[7];
    const float* aW1 = (const float*)d_in[8];
    const float* ab1 = (const float*)d_in[9];
    const float* aW2 = (const float*)d_in[10];
    const float* ab2 = (const float*)d_in[11];
    const float* aW3 = (const float*)d_in[12];
    const float* ab3 = (const float*)d_in[13];
    const float* cW1 = (const float*)d_in[14];
    const float* cb1 = (const float*)d_in[15];
    const float* cW2 = (const float*)d_in[16];
    const float* cb2 = (const float*)d_in[17];
    const float* cW3 = (const float*)d_in[18];
    const float* cb3 = (const float*)d_in[19];
    float* out = (float*)d_out;
    __bf16* wbf = (__bf16*)d_ws;  // needs SLAB*K*2 = ~1.39 MB of scratch

    prep_weights<<<(SLAB * Kk + 255) / 256, 256, 0, stream>>>(kW1, aW1, cW1, kW2, aW2, cW2,
                                                              kW3, aW3, cW3, wbf);
    qplex_main<<<Bsz / 128, 256, 0, stream>>>(states, actions, wbf, kb1, kb2, kb3,
                                              ab1, ab2, ab3, cb1, cb2, cb3, out);
}